// Round 11
// baseline (104.921 us; speedup 1.0000x reference)
//
#include <hip/hip_runtime.h>

#define NPIX 16384   // 128*128
#define NN   256     // max_nodes
#define CC   256     // NFEAT
#define HH   128     // SCORER_HIDDEN
#define EE   65280   // NN*(NN-1)
#define BB   4
#define NG   8       // histogram privatization groups
#define NWELEM 196608        // 3*256*256 per weight tensor
#define CONV_BLOCKS 384      // 2*NWELEM / 1024

__device__ __forceinline__ float bf_lo(unsigned u){ return __uint_as_float(u << 16); }
__device__ __forceinline__ float bf_hi(unsigned u){ return __uint_as_float(u & 0xFFFF0000u); }
__device__ __forceinline__ unsigned short f2bf(float f){
  unsigned b = __float_as_uint(f);
  return (unsigned short)((b + 0x7fffu + ((b >> 16) & 1u)) >> 16);
}
__device__ __forceinline__ float bf2f(unsigned short s){ return __uint_as_float(((unsigned)s) << 16); }

// ---------------- Kernel 1: top-k (blocks 0..3) + weight bf16 convert (blocks 4..387) ----
__global__ __launch_bounds__(1024) void k_topk(
    const float* __restrict__ jl, const float* __restrict__ off,
    int* __restrict__ topi, int* __restrict__ valid, float* __restrict__ inv_deg,
    float* __restrict__ out_nodes, float* __restrict__ Sbuf,
    const float* __restrict__ Wself_f, const float* __restrict__ Wnbr_f,
    unsigned short* __restrict__ wbf)   // [2*NWELEM]: Wself then Wnbr
{
  __shared__ int hist[NG][257];
  __shared__ int histT[256];
  __shared__ unsigned long long s_sel[NN];
  __shared__ unsigned long long s_T;
  __shared__ int s_digit, s_krem, s_cnt, s_vcnt, s_break;

  const int bid = blockIdx.x;
  const int tid = threadIdx.x;

  if (bid >= BB) {
    int i = (bid - BB) * 1024 + tid;        // 0 .. 2*NWELEM-1 exactly
    float v = (i < NWELEM) ? Wself_f[i] : Wnbr_f[i - NWELEM];
    wbf[i] = f2bf(v);
    return;
  }

  const int b = bid;
  const int grp = (tid >> 7) & (NG - 1);
  if (tid == 0) { s_cnt = 0; s_vcnt = 0; }

  {
    int l = tid >> 8, c = tid & 255;
    Sbuf[l*BB*CC + b*CC + c] = 0.0f;
  }

  unsigned long long rk[16];
  const float* p = jl + (size_t)b * NPIX;
  #pragma unroll
  for (int r = 0; r < 16; ++r) {
    int i = tid + (r << 10);
    float x = p[i];
    float pr = 1.0f / (1.0f + expf(-x));
    unsigned bits = __float_as_uint(pr);
    rk[r] = ((unsigned long long)bits << 32) | (unsigned)(0xFFFFFFFFu - (unsigned)i);
  }

  unsigned long long prefix = 0;
  int k = NN;
  int shift = 56;
  int brk = 0;
  for (int pass = 0; pass < 8 && !brk; ++pass) {
    shift = 56 - 8 * pass;
    for (int i = tid; i < NG * 257; i += 1024) ((int*)hist)[i] = 0;
    __syncthreads();
    unsigned long long pmask = (pass == 0) ? 0ULL : (~0ULL << (shift + 8));
    #pragma unroll
    for (int r = 0; r < 16; ++r) {
      unsigned long long kk = rk[r];
      if ((kk & pmask) == prefix)
        atomicAdd(&hist[grp][(int)((kk >> shift) & 255)], 1);
    }
    __syncthreads();
    if (tid < 256) {
      int t = 0;
      #pragma unroll
      for (int g = 0; g < NG; ++g) t += hist[g][tid];
      histT[tid] = t;
    }
    __syncthreads();
    if (tid < 64) {
      int h0 = histT[4*tid + 0], h1 = histT[4*tid + 1];
      int h2 = histT[4*tid + 2], h3 = histT[4*tid + 3];
      int tot = h0 + h1 + h2 + h3;
      int suf = tot;
      #pragma unroll
      for (int d = 1; d < 64; d <<= 1) {
        int o = __shfl_down(suf, d);
        if (tid + d < 64) suf += o;
      }
      int above = suf - tot;
      int c3 = h3 + above;
      int c2 = c3 + h2;
      int c1 = c2 + h1;
      int c0 = c1 + h0;
      if      (c3 >= k && above < k) { s_digit = 4*tid+3; s_krem = k - above; s_break = (h3 == 1); }
      else if (c2 >= k && c3    < k) { s_digit = 4*tid+2; s_krem = k - c3;    s_break = (h2 == 1); }
      else if (c1 >= k && c2    < k) { s_digit = 4*tid+1; s_krem = k - c2;    s_break = (h1 == 1); }
      else if (c0 >= k && c1    < k) { s_digit = 4*tid+0; s_krem = k - c1;    s_break = (h0 == 1); }
    }
    __syncthreads();
    prefix |= ((unsigned long long)s_digit) << shift;
    k = s_krem;
    brk = s_break;
  }

  if (shift == 0) {
    if (tid == 0) s_T = prefix;
  } else {
    unsigned long long known_mask = ~0ULL << shift;
    #pragma unroll
    for (int r = 0; r < 16; ++r)
      if ((rk[r] & known_mask) == prefix) s_T = rk[r];
  }
  __syncthreads();
  unsigned long long T = s_T;

  #pragma unroll
  for (int r = 0; r < 16; ++r) {
    unsigned long long kk = rk[r];
    if (kk >= T) { int pos = atomicAdd(&s_cnt, 1); s_sel[pos] = kk; }
  }
  __syncthreads();

  int my_rank = -1, my_v = 0;
  if (tid < NN) {
    unsigned long long mine = s_sel[tid];
    int rank = 0;
    #pragma unroll 16
    for (int j = 0; j < NN; ++j) rank += (s_sel[j] > mine) ? 1 : 0;
    unsigned bits = (unsigned)(mine >> 32);
    int v = bits > 0x3F000000u ? 1 : 0;
    int idx = (int)(0xFFFFFFFFu - (unsigned)(mine & 0xFFFFFFFFull));
    if (v) atomicAdd(&s_vcnt, 1);
    topi[b*NN + rank] = idx;
    valid[b*NN + rank] = v;
    int iy = idx >> 7;
    int ix = idx & 127;
    float yo = off[((size_t)b*2 + 0) * NPIX + idx];
    float xo = off[((size_t)b*2 + 1) * NPIX + idx];
    out_nodes[(b*NN + rank)*2 + 0] = ((float)ix + 0.5f + xo) * 4.0f;
    out_nodes[(b*NN + rank)*2 + 1] = ((float)iy + 0.5f + yo) * 4.0f;
    my_rank = rank; my_v = v;
  }
  __syncthreads();
  if (tid < NN) {
    int V = s_vcnt;
    inv_deg[b*NN + my_rank] = (my_v && V >= 2) ? 1.0f / (float)(V - 1) : 0.0f;
  }
}

// ---------------- Kernel 2: gather node features (bf16 out) + fused colsum into S0 ----------------
__global__ __launch_bounds__(256) void k_gather(
    const float* __restrict__ nmap, const int* __restrict__ topi,
    const int* __restrict__ valid, unsigned short* __restrict__ x, float* __restrict__ S0)
{
  const int bn = blockIdx.x;
  const int b = bn >> 8;
  const int c = threadIdx.x;
  int pix = topi[bn];
  int v = valid[bn];
  float val = v ? nmap[(((size_t)b*CC + c) << 14) + pix] : 0.0f;
  unsigned short hb = f2bf(val);
  x[(size_t)bn*CC + c] = hb;
  float valr = bf2f(hb);
  if (valr != 0.0f) atomicAdd(&S0[b*CC + c], valr);
}

// ---------------- Kernel 3: GNN layer, bf16 weights + bf16 x ----------------
// out[r][col] = relu(A1 + inv_r*(P2[col] - A2) + bias) * valid
// Block: 2 rows x 128 col-pairs x K-split 4 = 512 thr. Grid 512.
__global__ __launch_bounds__(512, 4) void k_gnn(
    const unsigned short* __restrict__ x, const float* __restrict__ S,
    const float* __restrict__ inv_deg, const int* __restrict__ valid,
    const unsigned short* __restrict__ Wself, const unsigned short* __restrict__ Wnbr,
    const float* __restrict__ bias, unsigned short* __restrict__ xout,
    float* __restrict__ Snext,     // may be null
    float* __restrict__ out_emb)   // may be null
{
  __shared__ float sx0[CC], sx1[CC], ss[CC];   // 3 KiB
  __shared__ float red[3][10][128];            // 15 KiB
  const int n0  = blockIdx.x * 2;              // global row, 0..1022
  const int b   = n0 >> 8;
  const int tid = threadIdx.x;
  const int cp  = tid & 127;                   // col pair
  const int kw  = tid >> 7;                    // 0..3 K-quarter
  const int col0 = cp << 1;

  if (tid < 128) {
    unsigned uu = ((const unsigned*)(x + (size_t)n0*CC))[tid];
    sx0[2*tid] = bf_lo(uu); sx0[2*tid+1] = bf_hi(uu);
  } else if (tid < 256) {
    int t = tid - 128;
    unsigned uu = ((const unsigned*)(x + (size_t)(n0+1)*CC))[t];
    sx1[2*t] = bf_lo(uu); sx1[2*t+1] = bf_hi(uu);
  } else if (tid < 320) {
    int t = tid - 256;
    ((float4*)ss)[t] = ((const float4*)(S + (size_t)b*CC))[t];
  }
  __syncthreads();

  const float4* x0v = (const float4*)sx0;
  const float4* x1v = (const float4*)sx1;
  const float4* ssv = (const float4*)ss;
  const unsigned* W1u = (const unsigned*)Wself;   // [c*128 + cp] -> cols (2cp, 2cp+1)
  const unsigned* W2u = (const unsigned*)Wnbr;

  float a1r0c0=0, a1r0c1=0, a1r1c0=0, a1r1c1=0;
  float a2r0c0=0, a2r0c1=0, a2r1c0=0, a2r1c1=0;
  float aSc0=0, aSc1=0;

  #pragma unroll 4
  for (int c4 = 0; c4 < 16; ++c4) {
    int q = (kw << 4) + c4;          // float4 index; c = 4q
    float4 xv0 = x0v[q];
    float4 xv1 = x1v[q];
    float4 sv  = ssv[q];
    int wb = (q << 2) * 128 + cp;
    unsigned u1a = W1u[wb];       unsigned u2a = W2u[wb];
    unsigned u1b = W1u[wb + 128]; unsigned u2b = W2u[wb + 128];
    unsigned u1c = W1u[wb + 256]; unsigned u2c = W2u[wb + 256];
    unsigned u1d = W1u[wb + 384]; unsigned u2d = W2u[wb + 384];

    float w1a0 = bf_lo(u1a), w1a1 = bf_hi(u1a);
    float w2a0 = bf_lo(u2a), w2a1 = bf_hi(u2a);
    a1r0c0 += xv0.x*w1a0; a1r0c1 += xv0.x*w1a1;
    a1r1c0 += xv1.x*w1a0; a1r1c1 += xv1.x*w1a1;
    a2r0c0 += xv0.x*w2a0; a2r0c1 += xv0.x*w2a1;
    a2r1c0 += xv1.x*w2a0; a2r1c1 += xv1.x*w2a1;
    aSc0   += sv.x *w2a0; aSc1   += sv.x *w2a1;

    float w1b0 = bf_lo(u1b), w1b1 = bf_hi(u1b);
    float w2b0 = bf_lo(u2b), w2b1 = bf_hi(u2b);
    a1r0c0 += xv0.y*w1b0; a1r0c1 += xv0.y*w1b1;
    a1r1c0 += xv1.y*w1b0; a1r1c1 += xv1.y*w1b1;
    a2r0c0 += xv0.y*w2b0; a2r0c1 += xv0.y*w2b1;
    a2r1c0 += xv1.y*w2b0; a2r1c1 += xv1.y*w2b1;
    aSc0   += sv.y *w2b0; aSc1   += sv.y *w2b1;

    float w1c0 = bf_lo(u1c), w1c1 = bf_hi(u1c);
    float w2c0 = bf_lo(u2c), w2c1 = bf_hi(u2c);
    a1r0c0 += xv0.z*w1c0; a1r0c1 += xv0.z*w1c1;
    a1r1c0 += xv1.z*w1c0; a1r1c1 += xv1.z*w1c1;
    a2r0c0 += xv0.z*w2c0; a2r0c1 += xv0.z*w2c1;
    a2r1c0 += xv1.z*w2c0; a2r1c1 += xv1.z*w2c1;
    aSc0   += sv.z *w2c0; aSc1   += sv.z *w2c1;

    float w1d0 = bf_lo(u1d), w1d1 = bf_hi(u1d);
    float w2d0 = bf_lo(u2d), w2d1 = bf_hi(u2d);
    a1r0c0 += xv0.w*w1d0; a1r0c1 += xv0.w*w1d1;
    a1r1c0 += xv1.w*w1d0; a1r1c1 += xv1.w*w1d1;
    a2r0c0 += xv0.w*w2d0; a2r0c1 += xv0.w*w2d1;
    a2r1c0 += xv1.w*w2d0; a2r1c1 += xv1.w*w2d1;
    aSc0   += sv.w *w2d0; aSc1   += sv.w *w2d1;
  }

  if (kw > 0) {
    red[kw-1][0][cp]=a1r0c0; red[kw-1][1][cp]=a1r0c1;
    red[kw-1][2][cp]=a1r1c0; red[kw-1][3][cp]=a1r1c1;
    red[kw-1][4][cp]=a2r0c0; red[kw-1][5][cp]=a2r0c1;
    red[kw-1][6][cp]=a2r1c0; red[kw-1][7][cp]=a2r1c1;
    red[kw-1][8][cp]=aSc0;   red[kw-1][9][cp]=aSc1;
  }
  __syncthreads();
  if (kw == 0) {
    #pragma unroll
    for (int g = 0; g < 3; ++g) {
      a1r0c0 += red[g][0][cp]; a1r0c1 += red[g][1][cp];
      a1r1c0 += red[g][2][cp]; a1r1c1 += red[g][3][cp];
      a2r0c0 += red[g][4][cp]; a2r0c1 += red[g][5][cp];
      a2r1c0 += red[g][6][cp]; a2r1c1 += red[g][7][cp];
      aSc0   += red[g][8][cp]; aSc1   += red[g][9][cp];
    }
    float bv0 = bias[col0], bv1 = bias[col0+1];
    int   va0 = valid[n0],  va1 = valid[n0+1];
    float in0 = inv_deg[n0], in1 = inv_deg[n0+1];
    float o00 = fmaxf(a1r0c0 + in0*(aSc0 - a2r0c0) + bv0, 0.f); o00 = va0 ? o00 : 0.f;
    float o01 = fmaxf(a1r0c1 + in0*(aSc1 - a2r0c1) + bv1, 0.f); o01 = va0 ? o01 : 0.f;
    float o10 = fmaxf(a1r1c0 + in1*(aSc0 - a2r1c0) + bv0, 0.f); o10 = va1 ? o10 : 0.f;
    float o11 = fmaxf(a1r1c1 + in1*(aSc1 - a2r1c1) + bv1, 0.f); o11 = va1 ? o11 : 0.f;

    unsigned short h00 = f2bf(o00), h01 = f2bf(o01), h10 = f2bf(o10), h11 = f2bf(o11);
    ((unsigned*)xout)[(size_t)n0*128 + cp]     = (unsigned)h00 | ((unsigned)h01 << 16);
    ((unsigned*)xout)[(size_t)(n0+1)*128 + cp] = (unsigned)h10 | ((unsigned)h11 << 16);
    if (out_emb) {
      float2 v0; v0.x = o00; v0.y = o01;
      float2 v1; v1.x = o10; v1.y = o11;
      *(float2*)&out_emb[(size_t)n0*CC + col0]     = v0;
      *(float2*)&out_emb[(size_t)(n0+1)*CC + col0] = v1;
    }
    if (Snext) {
      float cs0 = bf2f(h00) + bf2f(h10);
      float cs1 = bf2f(h01) + bf2f(h11);
      if (cs0 != 0.f) atomicAdd(&Snext[b*CC + col0],     cs0);
      if (cs1 != 0.f) atomicAdd(&Snext[b*CC + col0 + 1], cs1);
    }
  }
}

// ---------------- Kernel 4: u = x@Ws1[:C] (fp32 out), v_t = (x@Ws1[C:])^T (bf16 out) ----------------
__global__ __launch_bounds__(512) void k_uv(
    const unsigned short* __restrict__ x, const float* __restrict__ Ws1,
    float* __restrict__ u, unsigned short* __restrict__ vt)
{
  __shared__ float red[3][8][128];   // 12 KiB
  const int b   = blockIdx.x >> 6;
  const int n0  = (blockIdx.x & 63) * 4;
  const int tid = threadIdx.x;
  const int h   = tid & 127;
  const int kw  = tid >> 7;          // 0..3, 64 c's each

  const uint2* x2 = (const uint2*)(x + ((size_t)(b*NN + n0))*CC);  // 64 uint2/row
  float au0=0,au1=0,au2=0,au3=0, av0=0,av1=0,av2=0,av3=0;
  #pragma unroll 2
  for (int c4 = 0; c4 < 16; ++c4) {
    int q = kw*16 + c4;
    uint2 X0 = x2[q];
    uint2 X1 = x2[64 + q];
    uint2 X2 = x2[128 + q];
    uint2 X3 = x2[192 + q];
    float x0a=bf_lo(X0.x), x0b=bf_hi(X0.x), x0c=bf_lo(X0.y), x0d=bf_hi(X0.y);
    float x1a=bf_lo(X1.x), x1b=bf_hi(X1.x), x1c=bf_lo(X1.y), x1d=bf_hi(X1.y);
    float x2a=bf_lo(X2.x), x2b=bf_hi(X2.x), x2c=bf_lo(X2.y), x2d=bf_hi(X2.y);
    float x3a=bf_lo(X3.x), x3b=bf_hi(X3.x), x3c=bf_lo(X3.y), x3d=bf_hi(X3.y);
    int cb = q << 2;
    {
      float w1 = Ws1[(size_t)(cb+0)*HH + h];
      float w2 = Ws1[(size_t)(256+cb+0)*HH + h];
      au0 += x0a*w1; av0 += x0a*w2;
      au1 += x1a*w1; av1 += x1a*w2;
      au2 += x2a*w1; av2 += x2a*w2;
      au3 += x3a*w1; av3 += x3a*w2;
    }
    {
      float w1 = Ws1[(size_t)(cb+1)*HH + h];
      float w2 = Ws1[(size_t)(256+cb+1)*HH + h];
      au0 += x0b*w1; av0 += x0b*w2;
      au1 += x1b*w1; av1 += x1b*w2;
      au2 += x2b*w1; av2 += x2b*w2;
      au3 += x3b*w1; av3 += x3b*w2;
    }
    {
      float w1 = Ws1[(size_t)(cb+2)*HH + h];
      float w2 = Ws1[(size_t)(256+cb+2)*HH + h];
      au0 += x0c*w1; av0 += x0c*w2;
      au1 += x1c*w1; av1 += x1c*w2;
      au2 += x2c*w1; av2 += x2c*w2;
      au3 += x3c*w1; av3 += x3c*w2;
    }
    {
      float w1 = Ws1[(size_t)(cb+3)*HH + h];
      float w2 = Ws1[(size_t)(256+cb+3)*HH + h];
      au0 += x0d*w1; av0 += x0d*w2;
      au1 += x1d*w1; av1 += x1d*w2;
      au2 += x2d*w1; av2 += x2d*w2;
      au3 += x3d*w1; av3 += x3d*w2;
    }
  }
  if (kw > 0) {
    red[kw-1][0][h]=au0; red[kw-1][1][h]=au1; red[kw-1][2][h]=au2; red[kw-1][3][h]=au3;
    red[kw-1][4][h]=av0; red[kw-1][5][h]=av1; red[kw-1][6][h]=av2; red[kw-1][7][h]=av3;
  }
  __syncthreads();
  if (kw == 0) {
    float AU[4] = {au0,au1,au2,au3};
    float AV[4] = {av0,av1,av2,av3};
    #pragma unroll
    for (int g = 0; g < 3; ++g) {
      AU[0] += red[g][0][h]; AU[1] += red[g][1][h];
      AU[2] += red[g][2][h]; AU[3] += red[g][3][h];
      AV[0] += red[g][4][h]; AV[1] += red[g][5][h];
      AV[2] += red[g][6][h]; AV[3] += red[g][7][h];
    }
    #pragma unroll
    for (int r = 0; r < 4; ++r)
      u[((size_t)(b*NN + n0 + r))*HH + h] = AU[r];
    uint2 vpack;
    vpack.x = (unsigned)f2bf(AV[0]) | ((unsigned)f2bf(AV[1]) << 16);
    vpack.y = (unsigned)f2bf(AV[2]) | ((unsigned)f2bf(AV[3]) << 16);
    *(uint2*)(vt + ((size_t)(b*HH + h))*NN + n0) = vpack;
  }
}

// ---------------- Kernel 5: per-edge scorer, bf16 vt ----------------
__global__ __launch_bounds__(256) void k_edges(
    const float* __restrict__ u, const unsigned short* __restrict__ vt,
    const float* __restrict__ bs1, const float* __restrict__ Ws2,
    const float* __restrict__ bs2, const int* __restrict__ valid,
    float* __restrict__ out_logits, float* __restrict__ out_keep)
{
  const int b = blockIdx.x >> 8;
  const int i = blockIdx.x & 255;   // src node
  const int j = threadIdx.x;        // dst node
  const float4* u4  = (const float4*)(u + ((size_t)(b*NN + i))*HH);
  const float4* b14 = (const float4*)bs1;
  const float4* w24 = (const float4*)Ws2;
  const unsigned short* vrow = vt + (size_t)b*HH*NN;
  float acc = 0.f;
  #pragma unroll 4
  for (int h4 = 0; h4 < 32; ++h4) {
    float4 uu = u4[h4];
    float4 bb = b14[h4];
    float4 ww = w24[h4];
    int hb = h4 << 2;
    float t0 = uu.x + bb.x + bf2f(vrow[(size_t)(hb+0)*NN + j]);
    float t1 = uu.y + bb.y + bf2f(vrow[(size_t)(hb+1)*NN + j]);
    float t2 = uu.z + bb.z + bf2f(vrow[(size_t)(hb+2)*NN + j]);
    float t3 = uu.w + bb.w + bf2f(vrow[(size_t)(hb+3)*NN + j]);
    acc += fmaxf(t0, 0.f)*ww.x + fmaxf(t1, 0.f)*ww.y
         + fmaxf(t2, 0.f)*ww.z + fmaxf(t3, 0.f)*ww.w;
  }
  acc += bs2[0];
  if (j != i) {
    int e = i*255 + (j < i ? j : j - 1);
    int ev = valid[b*NN + i] & valid[b*NN + j];
    out_logits[(size_t)b*EE + e] = acc;
    out_keep  [(size_t)b*EE + e] = (acc > 0.f && ev) ? 1.0f : 0.0f;
  }
}

extern "C" void kernel_launch(void* const* d_in, const int* in_sizes, int n_in,
                              void* d_out, int out_size, void* d_ws, size_t ws_size,
                              hipStream_t stream) {
  const float* jl    = (const float*)d_in[0];
  const float* off   = (const float*)d_in[1];
  const float* nmap  = (const float*)d_in[2];
  const float* Wself = (const float*)d_in[3];
  const float* Wnbr  = (const float*)d_in[4];
  const float* bg    = (const float*)d_in[5];
  const float* Ws1   = (const float*)d_in[6];
  const float* bs1   = (const float*)d_in[7];
  const float* Ws2   = (const float*)d_in[8];
  const float* bs2   = (const float*)d_in[9];

  char* ws = (char*)d_ws;
  int*   topi    = (int*)  (ws + 0);                 //  4 KiB
  int*   valid   = (int*)  (ws + 4096);              //  4 KiB
  float* inv_deg = (float*)(ws + 8192);              //  4 KiB
  float* Sbuf    = (float*)(ws + 12288);             // 16 KiB (layer colsums)
  unsigned short* xa = (unsigned short*)(ws + 28672);            // 512 KiB bf16
  unsigned short* xb = (unsigned short*)(ws + 28672 + 1048576);  // 512 KiB bf16
  float* u       = (float*)(ws + 2125824);           //  512 KiB fp32
  unsigned short* vt = (unsigned short*)(ws + 2650112);          // 256 KiB bf16
  unsigned short* wbf = (unsigned short*)(ws + 3174400);         // 768 KiB bf16 weights

  float* out        = (float*)d_out;
  float* out_nodes  = out;                  // [4,256,2]   -> 2048
  float* out_emb    = out + 2048;           // [4,256,256] -> 262144
  float* out_logits = out + 264192;         // [4,65280]   -> 261120
  float* out_keep   = out + 525312;         // [4,65280]   -> 261120

  unsigned short* wbf_self = wbf;
  unsigned short* wbf_nbr  = wbf + NWELEM;

  hipLaunchKernelGGL(k_topk,   dim3(BB + CONV_BLOCKS), dim3(1024), 0, stream,
                     jl, off, topi, valid, inv_deg, out_nodes, Sbuf,
                     Wself, Wnbr, wbf);
  hipLaunchKernelGGL(k_gather, dim3(BB*NN),  dim3(256),  0, stream,
                     nmap, topi, valid, xa, Sbuf);

  unsigned short* xc = xa; unsigned short* xn = xb;
  for (int l = 0; l < 3; ++l) {
    hipLaunchKernelGGL(k_gnn, dim3(512), dim3(512), 0, stream,
                       xc, Sbuf + l*BB*CC, inv_deg, valid,
                       wbf_self + (size_t)l*CC*CC, wbf_nbr + (size_t)l*CC*CC, bg + l*CC,
                       xn,
                       (l < 2) ? (Sbuf + (l+1)*BB*CC) : (float*)nullptr,
                       (l == 2) ? out_emb : (float*)nullptr);
    unsigned short* t = xc; xc = xn; xn = t;
  }

  hipLaunchKernelGGL(k_uv,    dim3(256),   dim3(512), 0, stream, xc, Ws1, u, vt);
  hipLaunchKernelGGL(k_edges, dim3(BB*NN), dim3(256), 0, stream,
                     u, vt, bs1, Ws2, bs2, valid, out_logits, out_keep);
}

// Round 12
// 97.285 us; speedup vs baseline: 1.0785x; 1.0785x over previous
//
#include <hip/hip_runtime.h>

#define NPIX 16384   // 128*128
#define NN   256     // max_nodes
#define CC   256     // NFEAT
#define HH   128     // SCORER_HIDDEN
#define EE   65280   // NN*(NN-1)
#define BB   4
#define NG   8       // histogram privatization groups

typedef __attribute__((ext_vector_type(8))) short short8;   // bf16x8 MFMA frag
typedef __attribute__((ext_vector_type(4))) float f32x4;    // fp32x4 acc

__device__ __forceinline__ unsigned short f2bf(float f){
  unsigned b = __float_as_uint(f);
  return (unsigned short)((b + 0x7fffu + ((b >> 16) & 1u)) >> 16);
}
__device__ __forceinline__ float bf2f(unsigned short s){ return __uint_as_float(((unsigned)s) << 16); }
__device__ __forceinline__ float bf_lo(unsigned u){ return __uint_as_float(u << 16); }
__device__ __forceinline__ float bf_hi(unsigned u){ return __uint_as_float(u & 0xFFFF0000u); }

// ---------------- Kernel 0: weight convert fp32 -> bf16 (row-major + transposed) ----------------
// 6 matrices (Wself L0..2, Wnbr L0..2), 32x32 tiles. wbf[mat][l][c][n], wbfT[mat][l][n][c].
__global__ __launch_bounds__(256) void k_conv(
    const float* __restrict__ Wself, const float* __restrict__ Wnbr,
    unsigned short* __restrict__ wbf, unsigned short* __restrict__ wbfT)
{
  __shared__ float tile[32][33];
  const int blk = blockIdx.x;          // 6*64
  const int m = blk >> 6;
  const int t = blk & 63;
  const int tr = t >> 3, tc = t & 7;
  const float* src = (m < 3) ? (Wself + (size_t)m*65536) : (Wnbr + (size_t)(m-3)*65536);
  unsigned short* drow = ((m < 3) ? wbf  : (wbf  + 3*65536)) + (size_t)(m % 3)*65536;
  unsigned short* dT   = ((m < 3) ? wbfT : (wbfT + 3*65536)) + (size_t)(m % 3)*65536;
  const int r4 = threadIdx.x >> 5;     // 0..7
  const int cl = threadIdx.x & 31;
  #pragma unroll
  for (int rr = 0; rr < 4; ++rr) {
    int r = r4*4 + rr;
    float v = src[(size_t)(tr*32 + r)*256 + tc*32 + cl];
    drow[(size_t)(tr*32 + r)*256 + tc*32 + cl] = f2bf(v);
    tile[r][cl] = v;
  }
  __syncthreads();
  #pragma unroll
  for (int rr = 0; rr < 4; ++rr) {
    int r = r4*4 + rr;
    dT[(size_t)(tc*32 + r)*256 + tr*32 + cl] = f2bf(tile[cl][r]);   // [n][c]
  }
}

// ---------------- Kernel 1: sigmoid + exact top-k via register radix select ----------------
__global__ __launch_bounds__(1024) void k_topk(
    const float* __restrict__ jl, const float* __restrict__ off,
    int* __restrict__ topi, int* __restrict__ valid, float* __restrict__ inv_deg,
    float* __restrict__ out_nodes, float* __restrict__ Sbuf)
{
  __shared__ int hist[NG][257];
  __shared__ int histT[256];
  __shared__ unsigned long long s_sel[NN];
  __shared__ unsigned long long s_T;
  __shared__ int s_digit, s_krem, s_cnt, s_vcnt, s_break;

  const int b = blockIdx.x;
  const int tid = threadIdx.x;
  const int grp = (tid >> 7) & (NG - 1);
  if (tid == 0) { s_cnt = 0; s_vcnt = 0; }

  {
    int l = tid >> 8, c = tid & 255;
    Sbuf[l*BB*CC + b*CC + c] = 0.0f;
  }

  unsigned long long rk[16];
  const float* p = jl + (size_t)b * NPIX;
  #pragma unroll
  for (int r = 0; r < 16; ++r) {
    int i = tid + (r << 10);
    float x = p[i];
    float pr = 1.0f / (1.0f + expf(-x));
    unsigned bits = __float_as_uint(pr);
    rk[r] = ((unsigned long long)bits << 32) | (unsigned)(0xFFFFFFFFu - (unsigned)i);
  }

  unsigned long long prefix = 0;
  int k = NN;
  int shift = 56;
  int brk = 0;
  for (int pass = 0; pass < 8 && !brk; ++pass) {
    shift = 56 - 8 * pass;
    for (int i = tid; i < NG * 257; i += 1024) ((int*)hist)[i] = 0;
    __syncthreads();
    unsigned long long pmask = (pass == 0) ? 0ULL : (~0ULL << (shift + 8));
    #pragma unroll
    for (int r = 0; r < 16; ++r) {
      unsigned long long kk = rk[r];
      if ((kk & pmask) == prefix)
        atomicAdd(&hist[grp][(int)((kk >> shift) & 255)], 1);
    }
    __syncthreads();
    if (tid < 256) {
      int t = 0;
      #pragma unroll
      for (int g = 0; g < NG; ++g) t += hist[g][tid];
      histT[tid] = t;
    }
    __syncthreads();
    if (tid < 64) {
      int h0 = histT[4*tid + 0], h1 = histT[4*tid + 1];
      int h2 = histT[4*tid + 2], h3 = histT[4*tid + 3];
      int tot = h0 + h1 + h2 + h3;
      int suf = tot;
      #pragma unroll
      for (int d = 1; d < 64; d <<= 1) {
        int o = __shfl_down(suf, d);
        if (tid + d < 64) suf += o;
      }
      int above = suf - tot;
      int c3 = h3 + above;
      int c2 = c3 + h2;
      int c1 = c2 + h1;
      int c0 = c1 + h0;
      if      (c3 >= k && above < k) { s_digit = 4*tid+3; s_krem = k - above; s_break = (h3 == 1); }
      else if (c2 >= k && c3    < k) { s_digit = 4*tid+2; s_krem = k - c3;    s_break = (h2 == 1); }
      else if (c1 >= k && c2    < k) { s_digit = 4*tid+1; s_krem = k - c2;    s_break = (h1 == 1); }
      else if (c0 >= k && c1    < k) { s_digit = 4*tid+0; s_krem = k - c1;    s_break = (h0 == 1); }
    }
    __syncthreads();
    prefix |= ((unsigned long long)s_digit) << shift;
    k = s_krem;
    brk = s_break;
  }

  if (shift == 0) {
    if (tid == 0) s_T = prefix;
  } else {
    unsigned long long known_mask = ~0ULL << shift;
    #pragma unroll
    for (int r = 0; r < 16; ++r)
      if ((rk[r] & known_mask) == prefix) s_T = rk[r];
  }
  __syncthreads();
  unsigned long long T = s_T;

  #pragma unroll
  for (int r = 0; r < 16; ++r) {
    unsigned long long kk = rk[r];
    if (kk >= T) { int pos = atomicAdd(&s_cnt, 1); s_sel[pos] = kk; }
  }
  __syncthreads();

  int my_rank = -1, my_v = 0;
  if (tid < NN) {
    unsigned long long mine = s_sel[tid];
    int rank = 0;
    #pragma unroll 16
    for (int j = 0; j < NN; ++j) rank += (s_sel[j] > mine) ? 1 : 0;
    unsigned bits = (unsigned)(mine >> 32);
    int v = bits > 0x3F000000u ? 1 : 0;
    int idx = (int)(0xFFFFFFFFu - (unsigned)(mine & 0xFFFFFFFFull));
    if (v) atomicAdd(&s_vcnt, 1);
    topi[b*NN + rank] = idx;
    valid[b*NN + rank] = v;
    int iy = idx >> 7;
    int ix = idx & 127;
    float yo = off[((size_t)b*2 + 0) * NPIX + idx];
    float xo = off[((size_t)b*2 + 1) * NPIX + idx];
    out_nodes[(b*NN + rank)*2 + 0] = ((float)ix + 0.5f + xo) * 4.0f;
    out_nodes[(b*NN + rank)*2 + 1] = ((float)iy + 0.5f + yo) * 4.0f;
    my_rank = rank; my_v = v;
  }
  __syncthreads();
  if (tid < NN) {
    int V = s_vcnt;
    inv_deg[b*NN + my_rank] = (my_v && V >= 2) ? 1.0f / (float)(V - 1) : 0.0f;
  }
}

// ---------------- Kernel 2: gather node features (bf16 out) + fused colsum into S0 ----------------
__global__ __launch_bounds__(256) void k_gather(
    const float* __restrict__ nmap, const int* __restrict__ topi,
    const int* __restrict__ valid, unsigned short* __restrict__ x, float* __restrict__ S0)
{
  const int bn = blockIdx.x;
  const int b = bn >> 8;
  const int c = threadIdx.x;
  int pix = topi[bn];
  int v = valid[bn];
  float val = v ? nmap[(((size_t)b*CC + c) << 14) + pix] : 0.0f;
  unsigned short hb = f2bf(val);
  x[(size_t)bn*CC + c] = hb;
  float valr = bf2f(hb);
  if (valr != 0.0f) atomicAdd(&S0[b*CC + c], valr);
}

// ---------------- Kernel 3a: P2[b][col] = sum_c S[b][c] * W2bf[c][col] ----------------
__global__ __launch_bounds__(1024) void k_p2(
    const float* __restrict__ S, const unsigned short* __restrict__ W2,
    float* __restrict__ P2)
{
  __shared__ float red[3][256];
  const int b = blockIdx.x;
  const int tid = threadIdx.x;
  const int col = tid & 255;
  const int kw  = tid >> 8;          // 0..3, 64 c's each
  const float* Sb = S + b*CC;
  float acc = 0.f;
  #pragma unroll 8
  for (int ci = 0; ci < 64; ++ci) {
    int c = kw*64 + ci;
    acc += Sb[c] * bf2f(W2[(size_t)c*256 + col]);
  }
  if (kw > 0) red[kw-1][col] = acc;
  __syncthreads();
  if (kw == 0)
    P2[b*CC + col] = acc + red[0][col] + red[1][col] + red[2][col];
}

// ---------------- Kernel 3b: GNN layer via MFMA ----------------
// Block: 4 waves. Waves 0/1: A1 = X@W1 (cols cg*32..+31); waves 2/3: A2 = X@W2 same cols.
// M-tile 16 rows. Grid = 64 Mtiles x 8 colgroups = 512 blocks x 256 thr.
// A: x bf16 [row][k]; B: wT bf16 [n][k] (transposed store -> contiguous k frags).
// Frag maps (16x16x32): A row=l&15,k=(l>>4)*8+j; B col=l&15 same k; D col=l&15,row=(l>>4)*4+r.
__global__ __launch_bounds__(256) void k_gnn(
    const unsigned short* __restrict__ x, const float* __restrict__ P2,
    const float* __restrict__ inv_deg, const int* __restrict__ valid,
    const unsigned short* __restrict__ wT1, const unsigned short* __restrict__ wT2,
    const float* __restrict__ bias, unsigned short* __restrict__ xout,
    float* __restrict__ Snext,     // may be null
    float* __restrict__ out_emb)   // may be null
{
  __shared__ float sA1[16][33];
  __shared__ float sA2[16][33];
  const int mt = blockIdx.x >> 3;            // 0..63
  const int cg = blockIdx.x & 7;             // 0..7
  const int row0 = mt * 16;
  const int b = row0 >> 8;
  const int wave = threadIdx.x >> 6;
  const int lane = threadIdx.x & 63;

  const unsigned short* wT = (wave < 2) ? wT1 : wT2;
  const int colbase = cg*32 + (wave & 1)*16;
  const int arow = row0 + (lane & 15);
  const int koff = (lane >> 4) * 8;

  const short8* aptr = (const short8*)(x + (size_t)arow*256 + koff);
  const short8* bptr = (const short8*)(wT + (size_t)(colbase + (lane & 15))*256 + koff);

  f32x4 acc = {0.f, 0.f, 0.f, 0.f};
  #pragma unroll
  for (int kk = 0; kk < 8; ++kk) {
    short8 af = aptr[kk*4];      // advance 32 bf16 per chunk
    short8 bf = bptr[kk*4];
    acc = __builtin_amdgcn_mfma_f32_16x16x32_bf16(af, bf, acc, 0, 0, 0);
  }

  {
    float* dst = (wave < 2) ? &sA1[0][0] : &sA2[0][0];
    int ccol = (wave & 1)*16 + (lane & 15);
    #pragma unroll
    for (int r = 0; r < 4; ++r) {
      int crow = (lane >> 4)*4 + r;
      dst[crow*33 + ccol] = acc[r];
    }
  }
  __syncthreads();

  // epilogue: thread t -> row = t>>4, colpair cp2 = t&15 (cols 2*cp2, 2*cp2+1 of 32)
  const int row = threadIdx.x >> 4;
  const int cp2 = threadIdx.x & 15;
  const int gr = row0 + row;
  const int c0 = cg*32 + 2*cp2;
  float inv = inv_deg[gr];
  int   va  = valid[gr];
  float a10 = sA1[row][2*cp2], a11 = sA1[row][2*cp2+1];
  float a20 = sA2[row][2*cp2], a21 = sA2[row][2*cp2+1];
  float p0 = P2[b*CC + c0], p1 = P2[b*CC + c0 + 1];
  float o0 = fmaxf(a10 + inv*(p0 - a20) + bias[c0],     0.f); o0 = va ? o0 : 0.f;
  float o1 = fmaxf(a11 + inv*(p1 - a21) + bias[c0 + 1], 0.f); o1 = va ? o1 : 0.f;

  unsigned short h0 = f2bf(o0), h1 = f2bf(o1);
  ((unsigned*)xout)[(size_t)gr*128 + (cg*16 + cp2)] = (unsigned)h0 | ((unsigned)h1 << 16);
  if (out_emb) {
    float2 v; v.x = o0; v.y = o1;
    *(float2*)&out_emb[(size_t)gr*CC + c0] = v;
  }
  if (Snext) {
    __syncthreads();                 // all sA1 reads done
    sA1[row][2*cp2]   = bf2f(h0);    // colsum of rounded values (matches next layer's x)
    sA1[row][2*cp2+1] = bf2f(h1);
    __syncthreads();
    if (threadIdx.x < 32) {
      float s = 0.f;
      #pragma unroll
      for (int r = 0; r < 16; ++r) s += sA1[r][threadIdx.x];
      if (s != 0.f) atomicAdd(&Snext[b*CC + cg*32 + threadIdx.x], s);
    }
  }
}

// ---------------- Kernel 4: u = x@Ws1[:C] (fp32), v_t = (x@Ws1[C:])^T (fp32) ----------------
__global__ __launch_bounds__(512) void k_uv(
    const unsigned short* __restrict__ x, const float* __restrict__ Ws1,
    float* __restrict__ u, float* __restrict__ vt)
{
  __shared__ float red[3][8][128];   // 12 KiB
  const int b   = blockIdx.x >> 6;
  const int n0  = (blockIdx.x & 63) * 4;
  const int tid = threadIdx.x;
  const int h   = tid & 127;
  const int kw  = tid >> 7;          // 0..3, 64 c's each

  const uint2* x2 = (const uint2*)(x + ((size_t)(b*NN + n0))*CC);  // 64 uint2/row
  float au0=0,au1=0,au2=0,au3=0, av0=0,av1=0,av2=0,av3=0;
  #pragma unroll 2
  for (int c4 = 0; c4 < 16; ++c4) {
    int q = kw*16 + c4;
    uint2 X0 = x2[q];
    uint2 X1 = x2[64 + q];
    uint2 X2 = x2[128 + q];
    uint2 X3 = x2[192 + q];
    float x0a=bf_lo(X0.x), x0b=bf_hi(X0.x), x0c=bf_lo(X0.y), x0d=bf_hi(X0.y);
    float x1a=bf_lo(X1.x), x1b=bf_hi(X1.x), x1c=bf_lo(X1.y), x1d=bf_hi(X1.y);
    float x2a=bf_lo(X2.x), x2b=bf_hi(X2.x), x2c=bf_lo(X2.y), x2d=bf_hi(X2.y);
    float x3a=bf_lo(X3.x), x3b=bf_hi(X3.x), x3c=bf_lo(X3.y), x3d=bf_hi(X3.y);
    int cb = q << 2;
    {
      float w1 = Ws1[(size_t)(cb+0)*HH + h];
      float w2 = Ws1[(size_t)(256+cb+0)*HH + h];
      au0 += x0a*w1; av0 += x0a*w2;
      au1 += x1a*w1; av1 += x1a*w2;
      au2 += x2a*w1; av2 += x2a*w2;
      au3 += x3a*w1; av3 += x3a*w2;
    }
    {
      float w1 = Ws1[(size_t)(cb+1)*HH + h];
      float w2 = Ws1[(size_t)(256+cb+1)*HH + h];
      au0 += x0b*w1; av0 += x0b*w2;
      au1 += x1b*w1; av1 += x1b*w2;
      au2 += x2b*w1; av2 += x2b*w2;
      au3 += x3b*w1; av3 += x3b*w2;
    }
    {
      float w1 = Ws1[(size_t)(cb+2)*HH + h];
      float w2 = Ws1[(size_t)(256+cb+2)*HH + h];
      au0 += x0c*w1; av0 += x0c*w2;
      au1 += x1c*w1; av1 += x1c*w2;
      au2 += x2c*w1; av2 += x2c*w2;
      au3 += x3c*w1; av3 += x3c*w2;
    }
    {
      float w1 = Ws1[(size_t)(cb+3)*HH + h];
      float w2 = Ws1[(size_t)(256+cb+3)*HH + h];
      au0 += x0d*w1; av0 += x0d*w2;
      au1 += x1d*w1; av1 += x1d*w2;
      au2 += x2d*w1; av2 += x2d*w2;
      au3 += x3d*w1; av3 += x3d*w2;
    }
  }
  if (kw > 0) {
    red[kw-1][0][h]=au0; red[kw-1][1][h]=au1; red[kw-1][2][h]=au2; red[kw-1][3][h]=au3;
    red[kw-1][4][h]=av0; red[kw-1][5][h]=av1; red[kw-1][6][h]=av2; red[kw-1][7][h]=av3;
  }
  __syncthreads();
  if (kw == 0) {
    float AU[4] = {au0,au1,au2,au3};
    float AV[4] = {av0,av1,av2,av3};
    #pragma unroll
    for (int g = 0; g < 3; ++g) {
      AU[0] += red[g][0][h]; AU[1] += red[g][1][h];
      AU[2] += red[g][2][h]; AU[3] += red[g][3][h];
      AV[0] += red[g][4][h]; AV[1] += red[g][5][h];
      AV[2] += red[g][6][h]; AV[3] += red[g][7][h];
    }
    #pragma unroll
    for (int r = 0; r < 4; ++r) {
      u [((size_t)(b*NN + n0 + r))*HH + h] = AU[r];
      vt[((size_t)b*HH + h)*NN + (n0 + r)] = AV[r];
    }
  }
}

// ---------------- Kernel 5: per-edge scorer ----------------
__global__ __launch_bounds__(256) void k_edges(
    const float* __restrict__ u, const float* __restrict__ vt,
    const float* __restrict__ bs1, const float* __restrict__ Ws2,
    const float* __restrict__ bs2, const int* __restrict__ valid,
    float* __restrict__ out_logits, float* __restrict__ out_keep)
{
  const int b = blockIdx.x >> 8;
  const int i = blockIdx.x & 255;   // src node
  const int j = threadIdx.x;        // dst node
  const float4* u4  = (const float4*)(u + ((size_t)(b*NN + i))*HH);
  const float4* b14 = (const float4*)bs1;
  const float4* w24 = (const float4*)Ws2;
  const float* vrow = vt + (size_t)b*HH*NN;
  float acc = 0.f;
  #pragma unroll 4
  for (int h4 = 0; h4 < 32; ++h4) {
    float4 uu = u4[h4];
    float4 bb = b14[h4];
    float4 ww = w24[h4];
    int hb = h4 << 2;
    float t0 = uu.x + bb.x + vrow[(size_t)(hb+0)*NN + j];
    float t1 = uu.y + bb.y + vrow[(size_t)(hb+1)*NN + j];
    float t2 = uu.z + bb.z + vrow[(size_t)(hb+2)*NN + j];
    float t3 = uu.w + bb.w + vrow[(size_t)(hb+3)*NN + j];
    acc += fmaxf(t0, 0.f)*ww.x + fmaxf(t1, 0.f)*ww.y
         + fmaxf(t2, 0.f)*ww.z + fmaxf(t3, 0.f)*ww.w;
  }
  acc += bs2[0];
  if (j != i) {
    int e = i*255 + (j < i ? j : j - 1);
    int ev = valid[b*NN + i] & valid[b*NN + j];
    out_logits[(size_t)b*EE + e] = acc;
    out_keep  [(size_t)b*EE + e] = (acc > 0.f && ev) ? 1.0f : 0.0f;
  }
}

extern "C" void kernel_launch(void* const* d_in, const int* in_sizes, int n_in,
                              void* d_out, int out_size, void* d_ws, size_t ws_size,
                              hipStream_t stream) {
  const float* jl    = (const float*)d_in[0];
  const float* off   = (const float*)d_in[1];
  const float* nmap  = (const float*)d_in[2];
  const float* Wself = (const float*)d_in[3];
  const float* Wnbr  = (const float*)d_in[4];
  const float* bg    = (const float*)d_in[5];
  const float* Ws1   = (const float*)d_in[6];
  const float* bs1   = (const float*)d_in[7];
  const float* Ws2   = (const float*)d_in[8];
  const float* bs2   = (const float*)d_in[9];

  char* ws = (char*)d_ws;
  int*   topi    = (int*)  (ws + 0);                 //  4 KiB
  int*   valid   = (int*)  (ws + 4096);              //  4 KiB
  float* inv_deg = (float*)(ws + 8192);              //  4 KiB
  float* Sbuf    = (float*)(ws + 12288);             // 16 KiB (layer colsums)
  unsigned short* xa = (unsigned short*)(ws + 28672);    // 512 KiB bf16
  unsigned short* xb = (unsigned short*)(ws + 552960);   // 512 KiB bf16
  float* u       = (float*)(ws + 1077248);           // 512 KiB fp32
  float* vt      = (float*)(ws + 1601536);           // 512 KiB fp32
  float* P2      = (float*)(ws + 2125824);           //   4 KiB
  unsigned short* wbf  = (unsigned short*)(ws + 2129920); // 768 KiB row-major bf16
  unsigned short* wbfT = (unsigned short*)(ws + 2916352); // 768 KiB transposed bf16

  float* out        = (float*)d_out;
  float* out_nodes  = out;                  // [4,256,2]   -> 2048
  float* out_emb    = out + 2048;           // [4,256,256] -> 262144
  float* out_logits = out + 264192;         // [4,65280]   -> 261120
  float* out_keep   = out + 525312;         // [4,65280]   -> 261120

  hipLaunchKernelGGL(k_conv,   dim3(384),   dim3(256),  0, stream,
                     Wself, Wnbr, wbf, wbfT);
  hipLaunchKernelGGL(k_topk,   dim3(BB),    dim3(1024), 0, stream,
                     jl, off, topi, valid, inv_deg, out_nodes, Sbuf);
  hipLaunchKernelGGL(k_gather, dim3(BB*NN), dim3(256),  0, stream,
                     nmap, topi, valid, xa, Sbuf);

  unsigned short* xc = xa; unsigned short* xn = xb;
  for (int l = 0; l < 3; ++l) {
    hipLaunchKernelGGL(k_p2,  dim3(BB),  dim3(1024), 0, stream,
                       Sbuf + l*BB*CC, wbf + (size_t)(3 + l)*65536, P2);
    hipLaunchKernelGGL(k_gnn, dim3(512), dim3(256),  0, stream,
                       xc, P2, inv_deg, valid,
                       wbfT + (size_t)l*65536, wbfT + (size_t)(3 + l)*65536, bg + l*CC,
                       xn,
                       (l < 2) ? (Sbuf + (l+1)*BB*CC) : (float*)nullptr,
                       (l == 2) ? out_emb : (float*)nullptr);
    unsigned short* t = xc; xc = xn; xn = t;
  }

  hipLaunchKernelGGL(k_uv,    dim3(256),   dim3(512), 0, stream, xc, Ws1, u, vt);
  hipLaunchKernelGGL(k_edges, dim3(BB*NN), dim3(256), 0, stream,
                     u, vt, bs1, Ws2, bs2, valid, out_logits, out_keep);
}

// Round 13
// 81.598 us; speedup vs baseline: 1.2858x; 1.1923x over previous
//
#include <hip/hip_runtime.h>

#define NPIX 16384   // 128*128
#define NN   256     // max_nodes
#define CC   256     // NFEAT
#define HH   128     // SCORER_HIDDEN
#define EE   65280   // NN*(NN-1)
#define BB   4
#define NG   8       // histogram privatization groups

typedef __attribute__((ext_vector_type(8))) short short8;   // bf16x8 MFMA frag
typedef __attribute__((ext_vector_type(4))) float f32x4;    // fp32x4 acc

__device__ __forceinline__ unsigned short f2bf(float f){
  unsigned b = __float_as_uint(f);
  return (unsigned short)((b + 0x7fffu + ((b >> 16) & 1u)) >> 16);
}
__device__ __forceinline__ float bf2f(unsigned short s){ return __uint_as_float(((unsigned)s) << 16); }

// ---------------- Kernel 0: weight convert fp32 -> bf16 transposed ----------------
// blocks 0..383: 6 GNN mats -> wbfT[m][n][c].  blocks 384..447: Ws1 -> wuvT[col][c]
// (col<128 = u-cols from Ws1[:256], col>=128 = v-cols from Ws1[256:]).
__global__ __launch_bounds__(256) void k_conv(
    const float* __restrict__ Wself, const float* __restrict__ Wnbr,
    const float* __restrict__ Ws1,
    unsigned short* __restrict__ wbfT, unsigned short* __restrict__ wuvT)
{
  __shared__ float tile[32][33];
  const int blk = blockIdx.x;          // 0..447
  const int m = blk >> 6;              // 0..6
  const int t = blk & 63;
  const int r4 = threadIdx.x >> 5;     // 0..7
  const int cl = threadIdx.x & 31;
  if (m < 6) {
    const int tr = t >> 3, tc = t & 7;
    const float* src = (m < 3) ? (Wself + (size_t)m*65536) : (Wnbr + (size_t)(m-3)*65536);
    unsigned short* dT = wbfT + (size_t)m*65536;
    #pragma unroll
    for (int rr = 0; rr < 4; ++rr) {
      int r = r4*4 + rr;
      tile[r][cl] = src[(size_t)(tr*32 + r)*256 + tc*32 + cl];
    }
    __syncthreads();
    #pragma unroll
    for (int rr = 0; rr < 4; ++rr) {
      int r = r4*4 + rr;
      dT[(size_t)(tc*32 + r)*256 + tr*32 + cl] = f2bf(tile[cl][r]);   // [n][c]
    }
  } else {
    const int tr = t >> 2, tc = t & 3;   // tr 0..15 (512 rows), tc 0..3 (128 cols)
    #pragma unroll
    for (int rr = 0; rr < 4; ++rr) {
      int r = r4*4 + rr;
      tile[r][cl] = Ws1[(size_t)(tr*32 + r)*128 + tc*32 + cl];
    }
    __syncthreads();
    #pragma unroll
    for (int rr = 0; rr < 4; ++rr) {
      int r = r4*4 + rr;
      int h  = tc*32 + r;          // 0..127
      int cg = tr*32 + cl;         // 0..511
      int col = h + ((cg >= 256) ? 128 : 0);
      wuvT[(size_t)col*256 + (cg & 255)] = f2bf(tile[cl][r]);
    }
  }
}

// ---------------- Kernel 1: sigmoid + exact top-k via register radix select ----------------
__global__ __launch_bounds__(1024) void k_topk(
    const float* __restrict__ jl, const float* __restrict__ off,
    int* __restrict__ topi, int* __restrict__ valid, float* __restrict__ inv_deg,
    float* __restrict__ out_nodes, float* __restrict__ Sbuf)
{
  __shared__ int hist[NG][257];
  __shared__ int histT[256];
  __shared__ unsigned long long s_sel[NN];
  __shared__ unsigned long long s_T;
  __shared__ int s_digit, s_krem, s_cnt, s_vcnt, s_break;

  const int b = blockIdx.x;
  const int tid = threadIdx.x;
  const int grp = (tid >> 7) & (NG - 1);
  if (tid == 0) { s_cnt = 0; s_vcnt = 0; }

  {
    int l = tid >> 8, c = tid & 255;
    Sbuf[l*BB*CC + b*CC + c] = 0.0f;
  }

  unsigned long long rk[16];
  const float* p = jl + (size_t)b * NPIX;
  #pragma unroll
  for (int r = 0; r < 16; ++r) {
    int i = tid + (r << 10);
    float x = p[i];
    float pr = 1.0f / (1.0f + expf(-x));
    unsigned bits = __float_as_uint(pr);
    rk[r] = ((unsigned long long)bits << 32) | (unsigned)(0xFFFFFFFFu - (unsigned)i);
  }

  unsigned long long prefix = 0;
  int k = NN;
  int shift = 56;
  int brk = 0;
  for (int pass = 0; pass < 8 && !brk; ++pass) {
    shift = 56 - 8 * pass;
    for (int i = tid; i < NG * 257; i += 1024) ((int*)hist)[i] = 0;
    __syncthreads();
    unsigned long long pmask = (pass == 0) ? 0ULL : (~0ULL << (shift + 8));
    #pragma unroll
    for (int r = 0; r < 16; ++r) {
      unsigned long long kk = rk[r];
      if ((kk & pmask) == prefix)
        atomicAdd(&hist[grp][(int)((kk >> shift) & 255)], 1);
    }
    __syncthreads();
    if (tid < 256) {
      int t = 0;
      #pragma unroll
      for (int g = 0; g < NG; ++g) t += hist[g][tid];
      histT[tid] = t;
    }
    __syncthreads();
    if (tid < 64) {
      int h0 = histT[4*tid + 0], h1 = histT[4*tid + 1];
      int h2 = histT[4*tid + 2], h3 = histT[4*tid + 3];
      int tot = h0 + h1 + h2 + h3;
      int suf = tot;
      #pragma unroll
      for (int d = 1; d < 64; d <<= 1) {
        int o = __shfl_down(suf, d);
        if (tid + d < 64) suf += o;
      }
      int above = suf - tot;
      int c3 = h3 + above;
      int c2 = c3 + h2;
      int c1 = c2 + h1;
      int c0 = c1 + h0;
      if      (c3 >= k && above < k) { s_digit = 4*tid+3; s_krem = k - above; s_break = (h3 == 1); }
      else if (c2 >= k && c3    < k) { s_digit = 4*tid+2; s_krem = k - c3;    s_break = (h2 == 1); }
      else if (c1 >= k && c2    < k) { s_digit = 4*tid+1; s_krem = k - c2;    s_break = (h1 == 1); }
      else if (c0 >= k && c1    < k) { s_digit = 4*tid+0; s_krem = k - c1;    s_break = (h0 == 1); }
    }
    __syncthreads();
    prefix |= ((unsigned long long)s_digit) << shift;
    k = s_krem;
    brk = s_break;
  }

  if (shift == 0) {
    if (tid == 0) s_T = prefix;
  } else {
    unsigned long long known_mask = ~0ULL << shift;
    #pragma unroll
    for (int r = 0; r < 16; ++r)
      if ((rk[r] & known_mask) == prefix) s_T = rk[r];
  }
  __syncthreads();
  unsigned long long T = s_T;

  #pragma unroll
  for (int r = 0; r < 16; ++r) {
    unsigned long long kk = rk[r];
    if (kk >= T) { int pos = atomicAdd(&s_cnt, 1); s_sel[pos] = kk; }
  }
  __syncthreads();

  int my_rank = -1, my_v = 0;
  if (tid < NN) {
    unsigned long long mine = s_sel[tid];
    int rank = 0;
    #pragma unroll 16
    for (int j = 0; j < NN; ++j) rank += (s_sel[j] > mine) ? 1 : 0;
    unsigned bits = (unsigned)(mine >> 32);
    int v = bits > 0x3F000000u ? 1 : 0;
    int idx = (int)(0xFFFFFFFFu - (unsigned)(mine & 0xFFFFFFFFull));
    if (v) atomicAdd(&s_vcnt, 1);
    topi[b*NN + rank] = idx;
    valid[b*NN + rank] = v;
    int iy = idx >> 7;
    int ix = idx & 127;
    float yo = off[((size_t)b*2 + 0) * NPIX + idx];
    float xo = off[((size_t)b*2 + 1) * NPIX + idx];
    out_nodes[(b*NN + rank)*2 + 0] = ((float)ix + 0.5f + xo) * 4.0f;
    out_nodes[(b*NN + rank)*2 + 1] = ((float)iy + 0.5f + yo) * 4.0f;
    my_rank = rank; my_v = v;
  }
  __syncthreads();
  if (tid < NN) {
    int V = s_vcnt;
    inv_deg[b*NN + my_rank] = (my_v && V >= 2) ? 1.0f / (float)(V - 1) : 0.0f;
  }
}

// ---------------- Kernel 2: gather node features (bf16 out) + fused colsum into S0 ----------------
__global__ __launch_bounds__(256) void k_gather(
    const float* __restrict__ nmap, const int* __restrict__ topi,
    const int* __restrict__ valid, unsigned short* __restrict__ x, float* __restrict__ S0)
{
  const int bn = blockIdx.x;
  const int b = bn >> 8;
  const int c = threadIdx.x;
  int pix = topi[bn];
  int v = valid[bn];
  float val = v ? nmap[(((size_t)b*CC + c) << 14) + pix] : 0.0f;
  unsigned short hb = f2bf(val);
  x[(size_t)bn*CC + c] = hb;
  float valr = bf2f(hb);
  if (valr != 0.0f) atomicAdd(&S0[b*CC + c], valr);
}

// ---------------- Kernel 3: GNN layer via MFMA, P2 fused in-block ----------------
// out[r][col] = relu(A1 + inv_r*(P2[col] - A2) + bias) * valid
// 4 waves: w0/w1 -> A1 cols cg*32+{0..15,16..31}; w2/w3 -> A2 same. P2 slice computed
// in-block from S and wT2 (32 cols x 256 MACs over 256 threads).
__global__ __launch_bounds__(256) void k_gnn(
    const unsigned short* __restrict__ x, const float* __restrict__ S,
    const float* __restrict__ inv_deg, const int* __restrict__ valid,
    const unsigned short* __restrict__ wT1, const unsigned short* __restrict__ wT2,
    const float* __restrict__ bias, unsigned short* __restrict__ xout,
    float* __restrict__ Snext,     // may be null
    float* __restrict__ out_emb)   // may be null
{
  __shared__ float sA1[16][33];
  __shared__ float sA2[16][33];
  __shared__ float sP2p[8][33];
  __shared__ float sP2[32];
  const int mt = blockIdx.x >> 3;            // 0..63
  const int cg = blockIdx.x & 7;             // 0..7
  const int row0 = mt * 16;
  const int b = row0 >> 8;
  const int tid = threadIdx.x;
  const int wave = tid >> 6;
  const int lane = tid & 63;

  // ---- P2 slice: P2[cg*32 + cl] = sum_c S[c] * wT2[col][c] ----
  {
    const int cl = tid >> 3;         // 0..31
    const int kw = tid & 7;          // 0..7, 32 c's each
    const unsigned short* wrow = wT2 + (size_t)(cg*32 + cl)*256 + kw*32;
    const float* Sb = S + b*CC + kw*32;
    float a = 0.f;
    #pragma unroll 8
    for (int i = 0; i < 32; ++i) a += Sb[i] * bf2f(wrow[i]);
    sP2p[kw][cl] = a;
  }
  __syncthreads();
  if (tid < 32) {
    float s = 0.f;
    #pragma unroll
    for (int g = 0; g < 8; ++g) s += sP2p[g][tid];
    sP2[tid] = s;
  }

  // ---- MFMA GEMM ----
  const unsigned short* wT = (wave < 2) ? wT1 : wT2;
  const int colbase = cg*32 + (wave & 1)*16;
  const int arow = row0 + (lane & 15);
  const int koff = (lane >> 4) * 8;

  const short8* aptr = (const short8*)(x + (size_t)arow*256 + koff);
  const short8* bptr = (const short8*)(wT + (size_t)(colbase + (lane & 15))*256 + koff);

  f32x4 acc = {0.f, 0.f, 0.f, 0.f};
  #pragma unroll
  for (int kk = 0; kk < 8; ++kk) {
    short8 af = aptr[kk*4];      // advance 32 bf16 per chunk
    short8 bf = bptr[kk*4];
    acc = __builtin_amdgcn_mfma_f32_16x16x32_bf16(af, bf, acc, 0, 0, 0);
  }

  {
    float* dst = (wave < 2) ? &sA1[0][0] : &sA2[0][0];
    int ccol = (wave & 1)*16 + (lane & 15);
    #pragma unroll
    for (int r = 0; r < 4; ++r) {
      int crow = (lane >> 4)*4 + r;
      dst[crow*33 + ccol] = acc[r];
    }
  }
  __syncthreads();

  // epilogue: thread t -> row = t>>4, colpair cp2 = t&15
  const int row = tid >> 4;
  const int cp2 = tid & 15;
  const int gr = row0 + row;
  const int c0 = cg*32 + 2*cp2;
  float inv = inv_deg[gr];
  int   va  = valid[gr];
  float a10 = sA1[row][2*cp2], a11 = sA1[row][2*cp2+1];
  float a20 = sA2[row][2*cp2], a21 = sA2[row][2*cp2+1];
  float p0 = sP2[2*cp2], p1 = sP2[2*cp2+1];
  float o0 = fmaxf(a10 + inv*(p0 - a20) + bias[c0],     0.f); o0 = va ? o0 : 0.f;
  float o1 = fmaxf(a11 + inv*(p1 - a21) + bias[c0 + 1], 0.f); o1 = va ? o1 : 0.f;

  unsigned short h0 = f2bf(o0), h1 = f2bf(o1);
  ((unsigned*)xout)[(size_t)gr*128 + (cg*16 + cp2)] = (unsigned)h0 | ((unsigned)h1 << 16);
  if (out_emb) {
    float2 v; v.x = o0; v.y = o1;
    *(float2*)&out_emb[(size_t)gr*CC + c0] = v;
  }
  if (Snext) {
    __syncthreads();                 // all sA1 reads done
    sA1[row][2*cp2]   = bf2f(h0);    // colsum of rounded values (matches next layer's x)
    sA1[row][2*cp2+1] = bf2f(h1);
    __syncthreads();
    if (tid < 32) {
      float s = 0.f;
      #pragma unroll
      for (int r = 0; r < 16; ++r) s += sA1[r][tid];
      if (s != 0.f) atomicAdd(&Snext[b*CC + cg*32 + tid], s);
    }
  }
}

// ---------------- Kernel 4: u/vt via MFMA. Combined 256-col GEMM over wuvT ----------------
// cols 0..127 -> u[n][h]; cols 128..255 -> vt[h][n] (contiguous float4 store).
__global__ __launch_bounds__(256) void k_uv(
    const unsigned short* __restrict__ x, const unsigned short* __restrict__ wuvT,
    float* __restrict__ u, float* __restrict__ vt)
{
  const int mt = blockIdx.x >> 2;      // 0..63
  const int cg = blockIdx.x & 3;       // 0..3 (64 cols each)
  const int row0 = mt * 16;
  const int b = row0 >> 8;
  const int wave = threadIdx.x >> 6;
  const int lane = threadIdx.x & 63;
  const int col = cg*64 + wave*16 + (lane & 15);
  const int arow = row0 + (lane & 15);
  const int koff = (lane >> 4) * 8;
  const short8* aptr = (const short8*)(x + (size_t)arow*256 + koff);
  const short8* bptr = (const short8*)(wuvT + (size_t)col*256 + koff);
  f32x4 acc = {0.f, 0.f, 0.f, 0.f};
  #pragma unroll
  for (int kk = 0; kk < 8; ++kk)
    acc = __builtin_amdgcn_mfma_f32_16x16x32_bf16(aptr[kk*4], bptr[kk*4], acc, 0, 0, 0);
  const int rbase = row0 + (lane >> 4)*4;
  if (col < HH) {
    #pragma unroll
    for (int r = 0; r < 4; ++r)
      u[(size_t)(rbase + r)*HH + col] = acc[r];
  } else {
    float4 v; v.x = acc[0]; v.y = acc[1]; v.z = acc[2]; v.w = acc[3];
    *(float4*)&vt[(size_t)(b*HH + (col - HH))*NN + rbase] = v;
  }
}

// ---------------- Kernel 5: per-edge scorer ----------------
__global__ __launch_bounds__(256) void k_edges(
    const float* __restrict__ u, const float* __restrict__ vt,
    const float* __restrict__ bs1, const float* __restrict__ Ws2,
    const float* __restrict__ bs2, const int* __restrict__ valid,
    float* __restrict__ out_logits, float* __restrict__ out_keep)
{
  const int b = blockIdx.x >> 8;
  const int i = blockIdx.x & 255;   // src node
  const int j = threadIdx.x;        // dst node
  const float4* u4  = (const float4*)(u + ((size_t)(b*NN + i))*HH);
  const float4* b14 = (const float4*)bs1;
  const float4* w24 = (const float4*)Ws2;
  const float* vrow = vt + (size_t)b*HH*NN;
  float acc = 0.f;
  #pragma unroll 4
  for (int h4 = 0; h4 < 32; ++h4) {
    float4 uu = u4[h4];
    float4 bb = b14[h4];
    float4 ww = w24[h4];
    int hb = h4 << 2;
    float t0 = uu.x + bb.x + vrow[(size_t)(hb+0)*NN + j];
    float t1 = uu.y + bb.y + vrow[(size_t)(hb+1)*NN + j];
    float t2 = uu.z + bb.z + vrow[(size_t)(hb+2)*NN + j];
    float t3 = uu.w + bb.w + vrow[(size_t)(hb+3)*NN + j];
    acc += fmaxf(t0, 0.f)*ww.x + fmaxf(t1, 0.f)*ww.y
         + fmaxf(t2, 0.f)*ww.z + fmaxf(t3, 0.f)*ww.w;
  }
  acc += bs2[0];
  if (j != i) {
    int e = i*255 + (j < i ? j : j - 1);
    int ev = valid[b*NN + i] & valid[b*NN + j];
    out_logits[(size_t)b*EE + e] = acc;
    out_keep  [(size_t)b*EE + e] = (acc > 0.f && ev) ? 1.0f : 0.0f;
  }
}

extern "C" void kernel_launch(void* const* d_in, const int* in_sizes, int n_in,
                              void* d_out, int out_size, void* d_ws, size_t ws_size,
                              hipStream_t stream) {
  const float* jl    = (const float*)d_in[0];
  const float* off   = (const float*)d_in[1];
  const float* nmap  = (const float*)d_in[2];
  const float* Wself = (const float*)d_in[3];
  const float* Wnbr  = (const float*)d_in[4];
  const float* bg    = (const float*)d_in[5];
  const float* Ws1   = (const float*)d_in[6];
  const float* bs1   = (const float*)d_in[7];
  const float* Ws2   = (const float*)d_in[8];
  const float* bs2   = (const float*)d_in[9];

  char* ws = (char*)d_ws;
  int*   topi    = (int*)  (ws + 0);                 //  4 KiB
  int*   valid   = (int*)  (ws + 4096);              //  4 KiB
  float* inv_deg = (float*)(ws + 8192);              //  4 KiB
  float* Sbuf    = (float*)(ws + 12288);             // 16 KiB (layer colsums)
  unsigned short* xa = (unsigned short*)(ws + 28672);    // 512 KiB bf16
  unsigned short* xb = (unsigned short*)(ws + 552960);   // 512 KiB bf16
  float* u       = (float*)(ws + 1077248);           // 512 KiB fp32
  float* vt      = (float*)(ws + 1601536);           // 512 KiB fp32
  unsigned short* wbfT = (unsigned short*)(ws + 2125824); // 768 KiB transposed bf16
  unsigned short* wuvT = (unsigned short*)(ws + 2912256); // 128 KiB transposed bf16

  float* out        = (float*)d_out;
  float* out_nodes  = out;                  // [4,256,2]   -> 2048
  float* out_emb    = out + 2048;           // [4,256,256] -> 262144
  float* out_logits = out + 264192;         // [4,65280]   -> 261120
  float* out_keep   = out + 525312;         // [4,65280]   -> 261120

  hipLaunchKernelGGL(k_conv,   dim3(448),   dim3(256),  0, stream,
                     Wself, Wnbr, Ws1, wbfT, wuvT);
  hipLaunchKernelGGL(k_topk,   dim3(BB),    dim3(1024), 0, stream,
                     jl, off, topi, valid, inv_deg, out_nodes, Sbuf);
  hipLaunchKernelGGL(k_gather, dim3(BB*NN), dim3(256),  0, stream,
                     nmap, topi, valid, xa, Sbuf);

  unsigned short* xc = xa; unsigned short* xn = xb;
  for (int l = 0; l < 3; ++l) {
    hipLaunchKernelGGL(k_gnn, dim3(512), dim3(256),  0, stream,
                       xc, Sbuf + l*BB*CC, inv_deg, valid,
                       wbfT + (size_t)l*65536, wbfT + (size_t)(3 + l)*65536, bg + l*CC,
                       xn,
                       (l < 2) ? (Sbuf + (l+1)*BB*CC) : (float*)nullptr,
                       (l == 2) ? out_emb : (float*)nullptr);
    unsigned short* t = xc; xc = xn; xn = t;
  }

  hipLaunchKernelGGL(k_uv,    dim3(256),   dim3(256), 0, stream, xc, wuvT, u, vt);
  hipLaunchKernelGGL(k_edges, dim3(BB*NN), dim3(256), 0, stream,
                     u, vt, bs1, Ws2, bs2, valid, out_logits, out_keep);
}

// Round 14
// 77.869 us; speedup vs baseline: 1.3474x; 1.0479x over previous
//
#include <hip/hip_runtime.h>

#define NPIX 16384   // 128*128
#define NN   256     // max_nodes
#define CC   256     // NFEAT
#define HH   128     // SCORER_HIDDEN
#define EE   65280   // NN*(NN-1)
#define BB   4
#define NG   16      // histogram privatization groups (per wave)

typedef __attribute__((ext_vector_type(8))) short short8;   // bf16x8 MFMA frag
typedef __attribute__((ext_vector_type(4))) float f32x4;    // fp32x4 acc

__device__ __forceinline__ unsigned short f2bf(float f){
  unsigned b = __float_as_uint(f);
  return (unsigned short)((b + 0x7fffu + ((b >> 16) & 1u)) >> 16);
}
__device__ __forceinline__ float bf2f(unsigned short s){ return __uint_as_float(((unsigned)s) << 16); }

// ---------------- Kernel 1: top-k (blocks 0..3) + weight bf16 transpose (blocks 4..451) ----
// conv blocks: 1024 threads = one 32x32 tile element each.
// blocks 4..387: 6 GNN mats -> wbfT[m][n][c]. blocks 388..451: Ws1 -> wuvT[col][c].
__global__ __launch_bounds__(1024) void k_topk(
    const float* __restrict__ jl, const float* __restrict__ off,
    int* __restrict__ topi, int* __restrict__ valid, float* __restrict__ inv_deg,
    float* __restrict__ out_nodes, float* __restrict__ Sbuf,
    const float* __restrict__ Wself, const float* __restrict__ Wnbr,
    const float* __restrict__ Ws1,
    unsigned short* __restrict__ wbfT, unsigned short* __restrict__ wuvT)
{
  __shared__ int hist[NG][257];
  __shared__ int histT[256];
  __shared__ unsigned long long s_sel[NN];
  __shared__ unsigned long long s_T;
  __shared__ int s_digit, s_krem, s_cnt, s_vcnt, s_break;
  __shared__ float tile[32][33];

  const int bid = blockIdx.x;
  const int tid = threadIdx.x;

  if (bid >= BB) {
    // ---- weight transpose+convert: one 32x32 tile per block ----
    const int blk = bid - BB;            // 0..447
    const int m = blk >> 6;              // 0..6
    const int t = blk & 63;
    const int r  = tid >> 5;             // 0..31
    const int cl = tid & 31;
    if (m < 6) {
      const int tr = t >> 3, tc = t & 7;
      const float* src = (m < 3) ? (Wself + (size_t)m*65536) : (Wnbr + (size_t)(m-3)*65536);
      tile[r][cl] = src[(size_t)(tr*32 + r)*256 + tc*32 + cl];
      __syncthreads();
      wbfT[(size_t)m*65536 + (size_t)(tc*32 + r)*256 + tr*32 + cl] = f2bf(tile[cl][r]);
    } else {
      const int tr = t >> 2, tc = t & 3;   // tr 0..15 (512 rows), tc 0..3 (128 cols)
      tile[r][cl] = Ws1[(size_t)(tr*32 + r)*128 + tc*32 + cl];
      __syncthreads();
      int h  = tc*32 + r;          // 0..127
      int cg = tr*32 + cl;         // 0..511
      int col = h + ((cg >= 256) ? 128 : 0);
      wuvT[(size_t)col*256 + (cg & 255)] = f2bf(tile[cl][r]);
    }
    return;
  }

  const int b = bid;
  const int grp = tid >> 6;            // one private hist per wave
  if (tid == 0) { s_cnt = 0; s_vcnt = 0; }

  {
    int l = tid >> 8, c = tid & 255;
    Sbuf[l*BB*CC + b*CC + c] = 0.0f;
  }

  unsigned long long rk[16];
  const float* p = jl + (size_t)b * NPIX;
  #pragma unroll
  for (int r = 0; r < 16; ++r) {
    int i = tid + (r << 10);
    float x = p[i];
    float pr = 1.0f / (1.0f + expf(-x));
    unsigned bits = __float_as_uint(pr);
    rk[r] = ((unsigned long long)bits << 32) | (unsigned)(0xFFFFFFFFu - (unsigned)i);
  }

  unsigned long long prefix = 0;
  int k = NN;
  int shift = 56;
  int brk = 0;
  for (int pass = 0; pass < 8 && !brk; ++pass) {
    shift = 56 - 8 * pass;
    for (int i = tid; i < NG * 257; i += 1024) ((int*)hist)[i] = 0;
    __syncthreads();
    unsigned long long pmask = (pass == 0) ? 0ULL : (~0ULL << (shift + 8));
    #pragma unroll
    for (int r = 0; r < 16; ++r) {
      unsigned long long kk = rk[r];
      if ((kk & pmask) == prefix)
        atomicAdd(&hist[grp][(int)((kk >> shift) & 255)], 1);
    }
    __syncthreads();
    if (tid < 256) {
      int t = 0;
      #pragma unroll
      for (int g = 0; g < NG; ++g) t += hist[g][tid];
      histT[tid] = t;
    }
    __syncthreads();
    if (tid < 64) {
      int h0 = histT[4*tid + 0], h1 = histT[4*tid + 1];
      int h2 = histT[4*tid + 2], h3 = histT[4*tid + 3];
      int tot = h0 + h1 + h2 + h3;
      int suf = tot;
      #pragma unroll
      for (int d = 1; d < 64; d <<= 1) {
        int o = __shfl_down(suf, d);
        if (tid + d < 64) suf += o;
      }
      int above = suf - tot;
      int c3 = h3 + above;
      int c2 = c3 + h2;
      int c1 = c2 + h1;
      int c0 = c1 + h0;
      if      (c3 >= k && above < k) { s_digit = 4*tid+3; s_krem = k - above; s_break = (h3 == 1); }
      else if (c2 >= k && c3    < k) { s_digit = 4*tid+2; s_krem = k - c3;    s_break = (h2 == 1); }
      else if (c1 >= k && c2    < k) { s_digit = 4*tid+1; s_krem = k - c2;    s_break = (h1 == 1); }
      else if (c0 >= k && c1    < k) { s_digit = 4*tid+0; s_krem = k - c1;    s_break = (h0 == 1); }
    }
    __syncthreads();
    prefix |= ((unsigned long long)s_digit) << shift;
    k = s_krem;
    brk = s_break;
  }

  if (shift == 0) {
    if (tid == 0) s_T = prefix;
  } else {
    unsigned long long known_mask = ~0ULL << shift;
    #pragma unroll
    for (int r = 0; r < 16; ++r)
      if ((rk[r] & known_mask) == prefix) s_T = rk[r];
  }
  __syncthreads();
  unsigned long long T = s_T;

  #pragma unroll
  for (int r = 0; r < 16; ++r) {
    unsigned long long kk = rk[r];
    if (kk >= T) { int pos = atomicAdd(&s_cnt, 1); s_sel[pos] = kk; }
  }
  __syncthreads();

  int my_rank = -1, my_v = 0;
  if (tid < NN) {
    unsigned long long mine = s_sel[tid];
    int rank = 0;
    #pragma unroll 16
    for (int j = 0; j < NN; ++j) rank += (s_sel[j] > mine) ? 1 : 0;
    unsigned bits = (unsigned)(mine >> 32);
    int v = bits > 0x3F000000u ? 1 : 0;
    int idx = (int)(0xFFFFFFFFu - (unsigned)(mine & 0xFFFFFFFFull));
    if (v) atomicAdd(&s_vcnt, 1);
    topi[b*NN + rank] = idx;
    valid[b*NN + rank] = v;
    int iy = idx >> 7;
    int ix = idx & 127;
    float yo = off[((size_t)b*2 + 0) * NPIX + idx];
    float xo = off[((size_t)b*2 + 1) * NPIX + idx];
    out_nodes[(b*NN + rank)*2 + 0] = ((float)ix + 0.5f + xo) * 4.0f;
    out_nodes[(b*NN + rank)*2 + 1] = ((float)iy + 0.5f + yo) * 4.0f;
    my_rank = rank; my_v = v;
  }
  __syncthreads();
  if (tid < NN) {
    int V = s_vcnt;
    inv_deg[b*NN + my_rank] = (my_v && V >= 2) ? 1.0f / (float)(V - 1) : 0.0f;
  }
}

// ---------------- Kernel 2: gather node features (bf16 out) + fused colsum into S0 ----------------
__global__ __launch_bounds__(256) void k_gather(
    const float* __restrict__ nmap, const int* __restrict__ topi,
    const int* __restrict__ valid, unsigned short* __restrict__ x, float* __restrict__ S0)
{
  const int bn = blockIdx.x;
  const int b = bn >> 8;
  const int c = threadIdx.x;
  int pix = topi[bn];
  int v = valid[bn];
  float val = v ? nmap[(((size_t)b*CC + c) << 14) + pix] : 0.0f;
  unsigned short hb = f2bf(val);
  x[(size_t)bn*CC + c] = hb;
  float valr = bf2f(hb);
  if (valr != 0.0f) atomicAdd(&S0[b*CC + c], valr);
}

// ---------------- Kernel 3: GNN layer via MFMA, P2 fused in-block ----------------
__global__ __launch_bounds__(256) void k_gnn(
    const unsigned short* __restrict__ x, const float* __restrict__ S,
    const float* __restrict__ inv_deg, const int* __restrict__ valid,
    const unsigned short* __restrict__ wT1, const unsigned short* __restrict__ wT2,
    const float* __restrict__ bias, unsigned short* __restrict__ xout,
    float* __restrict__ Snext,     // may be null
    float* __restrict__ out_emb)   // may be null
{
  __shared__ float sA1[16][33];
  __shared__ float sA2[16][33];
  __shared__ float sP2p[8][33];
  __shared__ float sP2[32];
  const int mt = blockIdx.x >> 3;            // 0..63
  const int cg = blockIdx.x & 7;             // 0..7
  const int row0 = mt * 16;
  const int b = row0 >> 8;
  const int tid = threadIdx.x;
  const int wave = tid >> 6;
  const int lane = tid & 63;

  // ---- P2 slice: P2[cg*32 + cl] = sum_c S[c] * wT2[col][c] ----
  {
    const int cl = tid >> 3;         // 0..31
    const int kw = tid & 7;          // 0..7, 32 c's each
    const unsigned short* wrow = wT2 + (size_t)(cg*32 + cl)*256 + kw*32;
    const float* Sb = S + b*CC + kw*32;
    float a = 0.f;
    #pragma unroll 8
    for (int i = 0; i < 32; ++i) a += Sb[i] * bf2f(wrow[i]);
    sP2p[kw][cl] = a;
  }
  __syncthreads();
  if (tid < 32) {
    float s = 0.f;
    #pragma unroll
    for (int g = 0; g < 8; ++g) s += sP2p[g][tid];
    sP2[tid] = s;
  }

  // ---- MFMA GEMM ----
  const unsigned short* wT = (wave < 2) ? wT1 : wT2;
  const int colbase = cg*32 + (wave & 1)*16;
  const int arow = row0 + (lane & 15);
  const int koff = (lane >> 4) * 8;

  const short8* aptr = (const short8*)(x + (size_t)arow*256 + koff);
  const short8* bptr = (const short8*)(wT + (size_t)(colbase + (lane & 15))*256 + koff);

  f32x4 acc = {0.f, 0.f, 0.f, 0.f};
  #pragma unroll
  for (int kk = 0; kk < 8; ++kk) {
    short8 af = aptr[kk*4];      // advance 32 bf16 per chunk
    short8 bf = bptr[kk*4];
    acc = __builtin_amdgcn_mfma_f32_16x16x32_bf16(af, bf, acc, 0, 0, 0);
  }

  {
    float* dst = (wave < 2) ? &sA1[0][0] : &sA2[0][0];
    int ccol = (wave & 1)*16 + (lane & 15);
    #pragma unroll
    for (int r = 0; r < 4; ++r) {
      int crow = (lane >> 4)*4 + r;
      dst[crow*33 + ccol] = acc[r];
    }
  }
  __syncthreads();

  // epilogue: thread t -> row = t>>4, colpair cp2 = t&15
  const int row = tid >> 4;
  const int cp2 = tid & 15;
  const int gr = row0 + row;
  const int c0 = cg*32 + 2*cp2;
  float inv = inv_deg[gr];
  int   va  = valid[gr];
  float a10 = sA1[row][2*cp2], a11 = sA1[row][2*cp2+1];
  float a20 = sA2[row][2*cp2], a21 = sA2[row][2*cp2+1];
  float p0 = sP2[2*cp2], p1 = sP2[2*cp2+1];
  float o0 = fmaxf(a10 + inv*(p0 - a20) + bias[c0],     0.f); o0 = va ? o0 : 0.f;
  float o1 = fmaxf(a11 + inv*(p1 - a21) + bias[c0 + 1], 0.f); o1 = va ? o1 : 0.f;

  unsigned short h0 = f2bf(o0), h1 = f2bf(o1);
  ((unsigned*)xout)[(size_t)gr*128 + (cg*16 + cp2)] = (unsigned)h0 | ((unsigned)h1 << 16);
  if (out_emb) {
    float2 v; v.x = o0; v.y = o1;
    *(float2*)&out_emb[(size_t)gr*CC + c0] = v;
  }
  if (Snext) {
    __syncthreads();                 // all sA1 reads done
    sA1[row][2*cp2]   = bf2f(h0);    // colsum of rounded values (matches next layer's x)
    sA1[row][2*cp2+1] = bf2f(h1);
    __syncthreads();
    if (tid < 32) {
      float s = 0.f;
      #pragma unroll
      for (int r = 0; r < 16; ++r) s += sA1[r][tid];
      if (s != 0.f) atomicAdd(&Snext[b*CC + cg*32 + tid], s);
    }
  }
}

// ---------------- Kernel 4: u/vt via MFMA; bs1 folded into u ----------------
__global__ __launch_bounds__(256) void k_uv(
    const unsigned short* __restrict__ x, const unsigned short* __restrict__ wuvT,
    const float* __restrict__ bs1,
    float* __restrict__ u, float* __restrict__ vt)
{
  const int mt = blockIdx.x >> 2;      // 0..63
  const int cg = blockIdx.x & 3;       // 0..3 (64 cols each)
  const int row0 = mt * 16;
  const int b = row0 >> 8;
  const int wave = threadIdx.x >> 6;
  const int lane = threadIdx.x & 63;
  const int col = cg*64 + wave*16 + (lane & 15);
  const int arow = row0 + (lane & 15);
  const int koff = (lane >> 4) * 8;
  const short8* aptr = (const short8*)(x + (size_t)arow*256 + koff);
  const short8* bptr = (const short8*)(wuvT + (size_t)col*256 + koff);
  f32x4 acc = {0.f, 0.f, 0.f, 0.f};
  #pragma unroll
  for (int kk = 0; kk < 8; ++kk)
    acc = __builtin_amdgcn_mfma_f32_16x16x32_bf16(aptr[kk*4], bptr[kk*4], acc, 0, 0, 0);
  const int rbase = row0 + (lane >> 4)*4;
  if (col < HH) {
    float bv = bs1[col];
    #pragma unroll
    for (int r = 0; r < 4; ++r)
      u[(size_t)(rbase + r)*HH + col] = acc[r] + bv;
  } else {
    float4 v; v.x = acc[0]; v.y = acc[1]; v.z = acc[2]; v.w = acc[3];
    *(float4*)&vt[(size_t)(b*HH + (col - HH))*NN + rbase] = v;
  }
}

// ---------------- Kernel 5: per-edge scorer, float4 over j, 4-way h-split ----------------
// u has bs1 folded. Block = (b,i); 256 thr = 4 h-partitions x 64 j-quads.
__global__ __launch_bounds__(256) void k_edges(
    const float* __restrict__ u, const float* __restrict__ vt,
    const float* __restrict__ Ws2, const float* __restrict__ bs2,
    const int* __restrict__ valid,
    float* __restrict__ out_logits, float* __restrict__ out_keep)
{
  __shared__ float4 red[3][64];
  const int b = blockIdx.x >> 8;
  const int i = blockIdx.x & 255;
  const int tid = threadIdx.x;
  const int jq = tid & 63;
  const int kh = tid >> 6;             // h-partition 0..3 (32 h each)
  const float* urow = u + ((size_t)(b*NN + i))*HH + kh*32;
  const float* wrow = Ws2 + kh*32;
  const float4* vbase = (const float4*)(vt + (size_t)(b*HH + kh*32)*NN) + jq;
  float ax = 0.f, ay = 0.f, az = 0.f, aw = 0.f;
  #pragma unroll 8
  for (int h = 0; h < 32; ++h) {
    float uh = urow[h];
    float wh = wrow[h];
    float4 v = vbase[(size_t)h*64];
    ax += fmaxf(uh + v.x, 0.f)*wh;
    ay += fmaxf(uh + v.y, 0.f)*wh;
    az += fmaxf(uh + v.z, 0.f)*wh;
    aw += fmaxf(uh + v.w, 0.f)*wh;
  }
  if (kh > 0) {
    float4 t; t.x = ax; t.y = ay; t.z = az; t.w = aw;
    red[kh-1][jq] = t;
  }
  __syncthreads();
  if (kh == 0) {
    float4 r0 = red[0][jq], r1 = red[1][jq], r2 = red[2][jq];
    float bs = bs2[0];
    float lg0 = ax + r0.x + r1.x + r2.x + bs;
    float lg1 = ay + r0.y + r1.y + r2.y + bs;
    float lg2 = az + r0.z + r1.z + r2.z + bs;
    float lg3 = aw + r0.w + r1.w + r2.w + bs;
    int vi = valid[b*NN + i];
    float* Lb = out_logits + (size_t)b*EE;
    float* Kb = out_keep   + (size_t)b*EE;
    int j0 = 4*jq;
    {
      int j = j0;
      if (j != i) { int e = i*255 + (j < i ? j : j-1);
        Lb[e] = lg0; Kb[e] = (lg0 > 0.f && vi && valid[b*NN + j]) ? 1.0f : 0.0f; }
    }
    {
      int j = j0 + 1;
      if (j != i) { int e = i*255 + (j < i ? j : j-1);
        Lb[e] = lg1; Kb[e] = (lg1 > 0.f && vi && valid[b*NN + j]) ? 1.0f : 0.0f; }
    }
    {
      int j = j0 + 2;
      if (j != i) { int e = i*255 + (j < i ? j : j-1);
        Lb[e] = lg2; Kb[e] = (lg2 > 0.f && vi && valid[b*NN + j]) ? 1.0f : 0.0f; }
    }
    {
      int j = j0 + 3;
      if (j != i) { int e = i*255 + (j < i ? j : j-1);
        Lb[e] = lg3; Kb[e] = (lg3 > 0.f && vi && valid[b*NN + j]) ? 1.0f : 0.0f; }
    }
  }
}

extern "C" void kernel_launch(void* const* d_in, const int* in_sizes, int n_in,
                              void* d_out, int out_size, void* d_ws, size_t ws_size,
                              hipStream_t stream) {
  const float* jl    = (const float*)d_in[0];
  const float* off   = (const float*)d_in[1];
  const float* nmap  = (const float*)d_in[2];
  const float* Wself = (const float*)d_in[3];
  const float* Wnbr  = (const float*)d_in[4];
  const float* bg    = (const float*)d_in[5];
  const float* Ws1   = (const float*)d_in[6];
  const float* bs1   = (const float*)d_in[7];
  const float* Ws2   = (const float*)d_in[8];
  const float* bs2   = (const float*)d_in[9];

  char* ws = (char*)d_ws;
  int*   topi    = (int*)  (ws + 0);                 //  4 KiB
  int*   valid   = (int*)  (ws + 4096);              //  4 KiB
  float* inv_deg = (float*)(ws + 8192);              //  4 KiB
  float* Sbuf    = (float*)(ws + 12288);             // 16 KiB (layer colsums)
  unsigned short* xa = (unsigned short*)(ws + 28672);    // 512 KiB bf16
  unsigned short* xb = (unsigned short*)(ws + 552960);   // 512 KiB bf16
  float* u       = (float*)(ws + 1077248);           // 512 KiB fp32
  float* vt      = (float*)(ws + 1601536);           // 512 KiB fp32
  unsigned short* wbfT = (unsigned short*)(ws + 2125824); // 768 KiB transposed bf16
  unsigned short* wuvT = (unsigned short*)(ws + 2912256); // 128 KiB transposed bf16

  float* out        = (float*)d_out;
  float* out_nodes  = out;                  // [4,256,2]   -> 2048
  float* out_emb    = out + 2048;           // [4,256,256] -> 262144
  float* out_logits = out + 264192;         // [4,65280]   -> 261120
  float* out_keep   = out + 525312;         // [4,65280]   -> 261120

  hipLaunchKernelGGL(k_topk,   dim3(BB + 448), dim3(1024), 0, stream,
                     jl, off, topi, valid, inv_deg, out_nodes, Sbuf,
                     Wself, Wnbr, Ws1, wbfT, wuvT);
  hipLaunchKernelGGL(k_gather, dim3(BB*NN),    dim3(256),  0, stream,
                     nmap, topi, valid, xa, Sbuf);

  unsigned short* xc = xa; unsigned short* xn = xb;
  for (int l = 0; l < 3; ++l) {
    hipLaunchKernelGGL(k_gnn, dim3(512), dim3(256),  0, stream,
                       xc, Sbuf + l*BB*CC, inv_deg, valid,
                       wbfT + (size_t)l*65536, wbfT + (size_t)(3 + l)*65536, bg + l*CC,
                       xn,
                       (l < 2) ? (Sbuf + (l+1)*BB*CC) : (float*)nullptr,
                       (l == 2) ? out_emb : (float*)nullptr);
    unsigned short* t = xc; xc = xn; xn = t;
  }

  hipLaunchKernelGGL(k_uv,    dim3(256),   dim3(256), 0, stream, xc, wuvT, bs1, u, vt);
  hipLaunchKernelGGL(k_edges, dim3(BB*NN), dim3(256), 0, stream,
                     u, vt, Ws2, bs2, valid, out_logits, out_keep);
}